// Round 1
// baseline (601.624 us; speedup 1.0000x reference)
//
#include <hip/hip_runtime.h>
#include <stdint.h>

typedef _Float16 f16;
typedef _Float16 f16x8 __attribute__((ext_vector_type(8)));
typedef float f32x4 __attribute__((ext_vector_type(4)));
typedef int int4v __attribute__((ext_vector_type(4)));
typedef float float4v __attribute__((ext_vector_type(4)));

#define S_LEN 2048
#define D_DIM 64
#define QBLK 128
#define KBLK 64
#define NTHREADS 512
#define KSTEPS (S_LEN / KBLK)     // 32
#define MW_STRIDE (KSTEPS * 4)    // u16 words per row

__device__ __forceinline__ uint16_t f16_bits(f16 h) {
    union { f16 h; uint16_t u; } c; c.h = h; return c.u;
}

__global__ __launch_bounds__(NTHREADS, 4)
void sdpa_kernel(const float* __restrict__ Qg, const float* __restrict__ Kg,
                 const float* __restrict__ Vg, const int* __restrict__ Mg,
                 float* __restrict__ ProbOut, float* __restrict__ AttnOut)
{
    // LDS: 8 + 8 + 16 + 32 = 64 KB -> 2 blocks/CU
    __shared__ f16 Klds[KBLK * D_DIM];          // K tile [k][d], XOR-swizzled rows (128 B)
    __shared__ f16 Vtlds[D_DIM * KBLK];         // V^T tile [d][k], XOR-swizzled rows
    __shared__ f16 Plds[8 * 16 * KBLK];         // per-wave P tile [16 q][64 k], swizzled
    __shared__ uint16_t Mw[QBLK * MW_STRIDE];   // packed mask bits [row][kstep][i]

    const int tid  = threadIdx.x;
    const int wq   = tid >> 6;       // wave 0..7
    const int lane = tid & 63;
    const int g    = lane >> 4;      // lane group 0..3
    const int lr   = lane & 15;

    const int bh = blockIdx.x >> 4;  // 0..63  (b*16+h)
    const int qb = blockIdx.x & 15;  // q block 0..15

    const size_t qkv_base = (size_t)bh * S_LEN * D_DIM;
    const size_t mat_base = (size_t)bh * S_LEN * S_LEN;
    const int qw0 = qb * QBLK + wq * 16;   // wave's first absolute q row

    // ---- Q fragments: lane holds Q[qw0+lr][d = g*8 + i + 32*h] ----
    f16x8 qfrag[2];
    {
        const float* qp = Qg + qkv_base + (size_t)(qw0 + lr) * D_DIM + g * 8;
        #pragma unroll
        for (int h = 0; h < 2; ++h) {
            float4v a = *(const float4v*)(qp + 32 * h);
            float4v b = *(const float4v*)(qp + 32 * h + 4);
            f16x8 f;
            f[0]=(f16)a[0]; f[1]=(f16)a[1]; f[2]=(f16)a[2]; f[3]=(f16)a[3];
            f[4]=(f16)b[0]; f[5]=(f16)b[1]; f[6]=(f16)b[2]; f[7]=(f16)b[3];
            qfrag[h] = f;
        }
    }

    float m_r[4], l_r[4];
    #pragma unroll
    for (int r = 0; r < 4; ++r) { m_r[r] = -__builtin_inff(); l_r[r] = 0.f; }

    // K/V staging assignment
    const int srow = tid >> 3;            // 0..63
    const int scol = (tid & 7) * 8;       // 0..56
    const int sidx = (srow * D_DIM + scol) ^ ((srow & 7) << 3);
    const int vrp  = tid >> 4;            // 0..31  (krows 2*vrp, 2*vrp+1)
    const int vdb  = (tid & 15) * 4;      // d base

    // ================= sweep 1: online max/sum =================
    for (int ks = 0; ks < KSTEPS; ++ks) {
        const int k0 = ks * KBLK;
        {   // stage K tile (f32 -> f16, swizzled)
            const float* kp = Kg + qkv_base + (size_t)(k0 + srow) * D_DIM + scol;
            float4v a = *(const float4v*)kp;
            float4v b = *(const float4v*)(kp + 4);
            f16x8 f;
            f[0]=(f16)a[0]; f[1]=(f16)a[1]; f[2]=(f16)a[2]; f[3]=(f16)a[3];
            f[4]=(f16)b[0]; f[5]=(f16)b[1]; f[6]=(f16)b[2]; f[7]=(f16)b[3];
            *(f16x8*)(&Klds[sidx]) = f;
        }
        // mask loads (nontemporal, issued before barrier to overlap)
        int4v mi[4];
        #pragma unroll
        for (int rr = 0; rr < 4; ++rr) {
            int rl = g + 4 * rr;   // local row 0..15
            mi[rr] = __builtin_nontemporal_load(
                (const int4v*)(Mg + mat_base + (size_t)(qw0 + rl) * S_LEN + k0 + lr * 4));
        }
        __syncthreads();

        // pack mask bits: bit c of Mw[row][ks][i] = mask(row, col=4c+i)
        #pragma unroll
        for (int rr = 0; rr < 4; ++rr) {
            #pragma unroll
            for (int i = 0; i < 4; ++i) {
                uint64_t B = __ballot(mi[rr][i] != 0);
                if (lane < 4) {
                    int row = wq * 16 + lane + 4 * rr;   // row&3 == lane
                    Mw[row * MW_STRIDE + ks * 4 + (i ^ (lane & 3))] =
                        (uint16_t)(B >> (16 * lane));
                }
            }
        }

        // QK^T: c[ct] covers cols k0+16*ct .. +15
        f32x4 c[4];
        #pragma unroll
        for (int ct = 0; ct < 4; ++ct) {
            c[ct] = (f32x4){0.f, 0.f, 0.f, 0.f};
            #pragma unroll
            for (int h = 0; h < 2; ++h) {
                int rowl = 16 * ct + lr;
                int idx = (rowl * D_DIM + g * 8 + 32 * h) ^ ((rowl & 7) << 3);
                f16x8 kf = *(const f16x8*)(&Klds[idx]);
                c[ct] = __builtin_amdgcn_mfma_f32_16x16x32_f16(qfrag[h], kf, c[ct], 0, 0, 0);
            }
        }

        // scale + mask + online softmax stats (lane's rows: 4*g + r)
        #pragma unroll
        for (int r = 0; r < 4; ++r) {
            int row = wq * 16 + 4 * g + r;   // row&3 == r
            uint32_t w = Mw[row * MW_STRIDE + ks * 4 + ((lane & 3) ^ r)];
            float sv[4];
            float tmax = -__builtin_inff();
            #pragma unroll
            for (int ct = 0; ct < 4; ++ct) {
                float s = c[ct][r] * 0.125f;
                int cb = 4 * ct + (lr >> 2);
                s = ((w >> cb) & 1) ? -1e9f : s;
                sv[ct] = s;
                tmax = fmaxf(tmax, s);
            }
            #pragma unroll
            for (int off = 1; off < 16; off <<= 1)
                tmax = fmaxf(tmax, __shfl_xor(tmax, off, 64));
            float mn = fmaxf(m_r[r], tmax);
            float tsum = 0.f;
            #pragma unroll
            for (int ct = 0; ct < 4; ++ct) tsum += __expf(sv[ct] - mn);
            #pragma unroll
            for (int off = 1; off < 16; off <<= 1)
                tsum += __shfl_xor(tsum, off, 64);
            l_r[r] = l_r[r] * __expf(m_r[r] - mn) + tsum;
            m_r[r] = mn;
        }
        __syncthreads();
    }

    float inv_l[4];
    #pragma unroll
    for (int r = 0; r < 4; ++r) inv_l[r] = 1.f / l_r[r];

    f32x4 acc[4];
    #pragma unroll
    for (int dt = 0; dt < 4; ++dt) acc[dt] = (f32x4){0.f, 0.f, 0.f, 0.f};

    // ================= sweep 2: recompute, write attn, PV =================
    for (int ks = 0; ks < KSTEPS; ++ks) {
        const int k0 = ks * KBLK;
        {   // stage K tile (identical to sweep 1 -> bitwise-identical scores)
            const float* kp = Kg + qkv_base + (size_t)(k0 + srow) * D_DIM + scol;
            float4v a = *(const float4v*)kp;
            float4v b = *(const float4v*)(kp + 4);
            f16x8 f;
            f[0]=(f16)a[0]; f[1]=(f16)a[1]; f[2]=(f16)a[2]; f[3]=(f16)a[3];
            f[4]=(f16)b[0]; f[5]=(f16)b[1]; f[6]=(f16)b[2]; f[7]=(f16)b[3];
            *(f16x8*)(&Klds[sidx]) = f;
        }
        {   // stage V^T tile: Vt[d][k] (f32 -> f16, swizzled)
            const float* vp = Vg + qkv_base + (size_t)(k0 + 2 * vrp) * D_DIM + vdb;
            float4v a = *(const float4v*)vp;
            float4v b = *(const float4v*)(vp + D_DIM);
            #pragma unroll
            for (int j = 0; j < 4; ++j) {
                int d = vdb + j;
                uint32_t pk = (uint32_t)f16_bits((f16)a[j]) |
                              ((uint32_t)f16_bits((f16)b[j]) << 16);
                int idx = (d * KBLK + 2 * vrp) ^ ((d & 7) << 3);
                *(uint32_t*)(&Vtlds[idx]) = pk;
            }
        }
        __syncthreads();

        f32x4 c[4];
        #pragma unroll
        for (int ct = 0; ct < 4; ++ct) {
            c[ct] = (f32x4){0.f, 0.f, 0.f, 0.f};
            #pragma unroll
            for (int h = 0; h < 2; ++h) {
                int rowl = 16 * ct + lr;
                int idx = (rowl * D_DIM + g * 8 + 32 * h) ^ ((rowl & 7) << 3);
                f16x8 kf = *(const f16x8*)(&Klds[idx]);
                c[ct] = __builtin_amdgcn_mfma_f32_16x16x32_f16(qfrag[h], kf, c[ct], 0, 0, 0);
            }
        }

        // p = exp(s - m); write attn = p/l; stash p (f16) for PV
        #pragma unroll
        for (int r = 0; r < 4; ++r) {
            int row = wq * 16 + 4 * g + r;
            uint32_t w = Mw[row * MW_STRIDE + ks * 4 + ((lane & 3) ^ r)];
            int qrow = qw0 + 4 * g + r;
            #pragma unroll
            for (int ct = 0; ct < 4; ++ct) {
                float s = c[ct][r] * 0.125f;
                int cb = 4 * ct + (lr >> 2);
                s = ((w >> cb) & 1) ? -1e9f : s;
                float p = __expf(s - m_r[r]);
                int col = k0 + 16 * ct + lr;
                __builtin_nontemporal_store(p * inv_l[r],
                    AttnOut + mat_base + (size_t)qrow * S_LEN + col);
                int rowp = 4 * g + r;   // local 0..15
                int pidx = wq * 16 * KBLK +
                           ((rowp * KBLK + 16 * ct + lr) ^ ((rowp & 7) << 3));
                Plds[pidx] = (f16)p;
            }
        }

        // PV: acc[dt] += P(16x64) * V(64x64)  (same-wave LDS roundtrip)
        #pragma unroll
        for (int h = 0; h < 2; ++h) {
            int pidx = wq * 16 * KBLK + ((lr * KBLK + g * 8 + 32 * h) ^ ((lr & 7) << 3));
            f16x8 pa = *(const f16x8*)(&Plds[pidx]);
            #pragma unroll
            for (int dt = 0; dt < 4; ++dt) {
                int rowd = 16 * dt + lr;
                int vidx = (rowd * KBLK + g * 8 + 32 * h) ^ ((rowd & 7) << 3);
                f16x8 vf = *(const f16x8*)(&Vtlds[vidx]);
                acc[dt] = __builtin_amdgcn_mfma_f32_16x16x32_f16(pa, vf, acc[dt], 0, 0, 0);
            }
        }
        __syncthreads();
    }

    // epilogue: prob = acc / l
    #pragma unroll
    for (int dt = 0; dt < 4; ++dt) {
        #pragma unroll
        for (int r = 0; r < 4; ++r) {
            int qrow = qw0 + 4 * g + r;
            ProbOut[qkv_base + (size_t)qrow * D_DIM + 16 * dt + lr] = acc[dt][r] * inv_l[r];
        }
    }
}

extern "C" void kernel_launch(void* const* d_in, const int* in_sizes, int n_in,
                              void* d_out, int out_size, void* d_ws, size_t ws_size,
                              hipStream_t stream)
{
    const float* Q = (const float*)d_in[0];
    const float* K = (const float*)d_in[1];
    const float* V = (const float*)d_in[2];
    const int*   M = (const int*)d_in[3];

    float* prob = (float*)d_out;                              // [4,16,2048,64]
    float* attn = prob + (size_t)4 * 16 * 2048 * 64;          // [4,16,2048,2048]

    dim3 grid(64 * (S_LEN / QBLK));   // 64 (b,h) x 16 q-blocks = 1024
    dim3 block(NTHREADS);
    sdpa_kernel<<<grid, block, 0, stream>>>(Q, K, V, M, prob, attn);
}